// Round 1
// baseline (110.722 us; speedup 1.0000x reference)
//
#include <hip/hip_runtime.h>
#include <math.h>

#define B   8
#define S   256
#define NT  50
#define E   64
#define NTE (NT * E)
#define EPSF 1e-16f
#define LOG2E 1.4426950408889634f

#define NW        4                 // waves per block
#define LL_BLOCKS (B * S / 2)       // 1024 blocks; each handles rows (ih, S-1-ih)
#define IN_BLOCKS (B * NT)          // 400 blocks
#define NBLK      (LL_BLOCKS + IN_BLOCKS)

// Completion counter for last-block finalize. Lives in module .data (NOT the
// harness-poisoned workspace). Zero at module load; the finalizing block
// resets it to 0 each launch with a device-scope RMW, so graph replays work.
__device__ int g_done = 0;

__device__ __forceinline__ float softplus(float x) {
    if (x > 20.0f) return x;
    return log1pf(__expf(x));
}

__device__ __forceinline__ float wave_reduce_sum(float v) {
    #pragma unroll
    for (int off = 32; off > 0; off >>= 1)
        v += __shfl_down(v, off, 64);
    return v;  // lane 0 holds the sum
}

// ---------------------------------------------------------------------------
// Single fused kernel. Grid = NBLK, 256 threads (4 waves).
//
// LL blocks: batch b, row pair (ih, 255-ih) -> uniform 255 inner iters/block.
// Events staged as float4 (t, ty*E, ty*NTE, 0) so the inner loop has zero
// integer multiplies. exp folded to exp2 with log2e pre-multiplied into the
// hoisted -emb_i term (one fewer v_mul per iteration vs __expf).
//
// Integral blocks: (b,k) per block, waves split the i-loop, invalid events
// predicated out.
//
// Last block to finish (device-scope atomic counter, release/acquire via
// __threadfence) runs the finalize reduction and writes out[0].
// ---------------------------------------------------------------------------
__global__ __launch_bounds__(64 * NW) void main_kernel(
    const float* __restrict__ times, const int* __restrict__ types,
    const int* __restrict__ Tp,
    const float* __restrict__ emb,  const float* __restrict__ a,
    const float* __restrict__ Amat, const float* __restrict__ Pmat,
    float* __restrict__ ws_ll, float* __restrict__ ws_int,
    float* __restrict__ out)
{
    const int tid = threadIdx.x;
    const int e   = tid & 63;
    const int w   = tid >> 6;
    const int bid = blockIdx.x;
    const bool is_ll = (bid < LL_BLOCKS);
    const int b = is_ll ? (bid / (S / 2)) : ((bid - LL_BLOCKS) / NT);

    __shared__ __align__(16) float  s_emb[NTE];   // 12.8 KB, lane-contiguous
    __shared__ __align__(16) float4 s_ev[S];      // (t, ty*E, ty*NTE, 0) as float bits
    __shared__ float  s_part[2][NW][E];
    __shared__ float  s_row[2];
    __shared__ int    s_fin;

    // stage emb with float4 (800 vec4 loads across 256 threads)
    {
        const float4* __restrict__ emb4 = (const float4*)emb;
        float4* s4 = (float4*)s_emb;
        for (int idx = tid; idx < NTE / 4; idx += 64 * NW)
            s4[idx] = emb4[idx];
    }
    for (int j = tid; j < S; j += 64 * NW) {
        const int ty = types[b * S + j];
        s_ev[j] = make_float4(times[b * S + j],
                              __int_as_float(ty * E),
                              __int_as_float(ty * NTE), 0.0f);
    }
    __syncthreads();

    if (is_ll) {
        const int ih = bid % (S / 2);
        const int rows[2] = { ih, S - 1 - ih };
        #pragma unroll
        for (int r = 0; r < 2; ++r) {
            const int   i      = rows[r];
            const float t_i    = s_ev[i].x;
            const int   col    = __float_as_int(s_ev[i].y) + e;  // ty_i*E + e
            const float negEi2 = -s_emb[col] * LOG2E;            // fold log2e

            float macc = 0.0f;
            #pragma unroll 8
            for (int j = w; j < i; j += NW) {
                const float4 ev  = s_ev[j];
                const float dtj  = t_i - ev.x;
                const int   base = __float_as_int(ev.z) + col;   // tyj*NTE + col
                const float ej   = s_emb[__float_as_int(ev.y) + e];
                const float Pe   = Pmat[base];
                const float Ae   = Amat[base];
                macc = fmaf(Ae * ej, exp2f(negEi2 * Pe * ej * dtj), macc);
            }
            s_part[r][w][e] = macc;
        }
        __syncthreads();
        if (w < 2) {
            const int   i     = rows[w];
            const float t_i   = s_ev[i].x;
            const int   col   = __float_as_int(s_ev[i].y) + e;
            const float emb_i = s_emb[col];
            float mt = 0.0f;
            #pragma unroll
            for (int q = 0; q < NW; ++q) mt += s_part[w][q][e];
            const float sp    = softplus(fmaf(emb_i, mt, emb_i * a[col]));
            const float inten = wave_reduce_sum(sp);
            if (e == 0)
                s_row[w] = (t_i >= 0.0f) ? logf(inten + EPSF) : 0.0f;
        }
        __syncthreads();
        if (tid == 0) ws_ll[bid] = s_row[0] + s_row[1];
    } else {
        const int   k      = (bid - LL_BLOCKS) % NT;
        const float Tf     = (float)(*Tp);
        const int   colk   = k * E + e;
        const float embk   = s_emb[colk];
        const float negEk2 = -embk * LOG2E;

        float acc = 0.0f;
        #pragma unroll 8
        for (int i = w; i < S; i += NW) {
            const float4 ev  = s_ev[i];
            const float dT   = Tf - ev.x;
            const int   base = __float_as_int(ev.z) + colk;
            const float et   = s_emb[__float_as_int(ev.y) + e];
            const float c    = Amat[base] * et * exp2f(negEk2 * Pmat[base] * et * dT);
            acc += (ev.x >= 0.0f) ? c : 0.0f;   // predicated, no branch
        }
        s_part[0][w][e] = acc;
        __syncthreads();
        if (w == 0) {
            float mt = 0.0f;
            #pragma unroll
            for (int q = 0; q < NW; ++q) mt += s_part[0][q][e];
            const float sp = softplus(fmaf(embk, mt, embk * a[colk]));
            const float s  = wave_reduce_sum(sp);
            if (e == 0) ws_int[bid - LL_BLOCKS] = s;
        }
    }

    // ------------------------------------------------------------------
    // Completion: the ws write above was done by tid 0 (both paths), so
    // tid 0's release fence orders it before the counter increment.
    // ------------------------------------------------------------------
    if (tid == 0) {
        __threadfence();                       // release: flush ws write
        const int old = atomicAdd(&g_done, 1); // device-scope by default
        s_fin = (old == NBLK - 1) ? 1 : 0;
    }
    __syncthreads();
    if (s_fin == 0) return;

    __threadfence();                           // acquire: invalidate stale lines

    // ------------------------------------------------------------------
    // Finalize (executed by exactly one block, all 256 threads).
    // ------------------------------------------------------------------
    const float Tf = (float)(*Tp);

    float llp = 0.0f;
    for (int idx = tid; idx < LL_BLOCKS; idx += 256) llp += ws_ll[idx];
    float bs = 0.0f;
    for (int idx = tid; idx < NTE; idx += 256) bs += softplus(s_emb[idx] * a[idx]);

    __shared__ float red[256], red2[256];
    red[tid] = llp; red2[tid] = bs;

    __shared__ float s_first[B], s_lastt[B], s_iT[B], s_any[B];
    const int lane = tid & 63;
    for (int bb = w; bb < B; bb += NW) {
        float mn = 1e30f, mx = -1e30f;
        #pragma unroll
        for (int q = 0; q < S / 64; ++q) {
            const float tv = times[bb * S + q * 64 + lane];
            const bool valid = (tv >= 0.0f);
            mn = fminf(mn, valid ? tv : 1e30f);
            mx = fmaxf(mx, valid ? tv : -1e30f);
        }
        float iv = (lane < NT) ? ws_int[bb * NT + lane] : 0.0f;
        #pragma unroll
        for (int off = 32; off > 0; off >>= 1) {
            mn = fminf(mn, __shfl_down(mn, off, 64));
            mx = fmaxf(mx, __shfl_down(mx, off, 64));
            iv += __shfl_down(iv, off, 64);
        }
        if (lane == 0) {
            const bool any_valid = (mn < 1e29f);
            s_any[bb]   = any_valid ? 1.0f : 0.0f;
            s_first[bb] = any_valid ? mn : 0.0f;
            s_lastt[bb] = any_valid ? mx : 0.0f;
            s_iT[bb]    = iv;
        }
    }
    __syncthreads();

    for (int off = 128; off > 0; off >>= 1) {
        if (tid < off) { red[tid] += red[tid + off]; red2[tid] += red2[tid + off]; }
        __syncthreads();
    }

    if (tid == 0) {
        const float base_sum = red2[0];
        float integral = 0.0f;
        #pragma unroll
        for (int bb = 0; bb < B; ++bb) {
            integral += (s_any[bb] > 0.5f)
                ? s_iT[bb] * (Tf - s_lastt[bb]) + base_sum * s_first[bb]
                : base_sum * Tf;
        }
        out[0] = integral - red[0];
        atomicExch(&g_done, 0);   // device-scope reset for next launch/replay
    }
}

extern "C" void kernel_launch(void* const* d_in, const int* in_sizes, int n_in,
                              void* d_out, int out_size, void* d_ws, size_t ws_size,
                              hipStream_t stream) {
    const float* times = (const float*)d_in[0];
    const int*   types = (const int*)d_in[1];
    const int*   Tp    = (const int*)d_in[2];
    const float* emb   = (const float*)d_in[3];
    const float* a     = (const float*)d_in[4];
    const float* Amat  = (const float*)d_in[5];
    const float* Pmat  = (const float*)d_in[6];

    float* ws     = (float*)d_ws;
    float* ws_ll  = ws;                  // [0, 1024)
    float* ws_int = ws + LL_BLOCKS;      // [1024, 1424)
    float* out    = (float*)d_out;

    main_kernel<<<NBLK, 64 * NW, 0, stream>>>(
        times, types, Tp, emb, a, Amat, Pmat, ws_ll, ws_int, out);
}

// Round 2
// 98.002 us; speedup vs baseline: 1.1298x; 1.1298x over previous
//
#include <hip/hip_runtime.h>
#include <math.h>

#define B   8
#define S   256
#define NT  50
#define E   64
#define NTE (NT * E)
#define EPSF 1e-16f
#define LOG2E 1.4426950408889634f

#define NW        8                 // waves per block (512 threads)
#define NTHREADS  (64 * NW)
#define LL_BLOCKS (B * S / 2)       // 1024 blocks; each handles rows (ih, S-1-ih)
#define IN_BLOCKS (B * NT)          // 400 blocks

__device__ __forceinline__ float softplus(float x) {
    if (x > 20.0f) return x;
    return log1pf(__expf(x));
}

__device__ __forceinline__ float wave_reduce_sum(float v) {
    #pragma unroll
    for (int off = 32; off > 0; off >>= 1)
        v += __shfl_down(v, off, 64);
    return v;  // lane 0 holds the sum
}

// ---------------------------------------------------------------------------
// Main kernel. Grid = LL_BLOCKS + IN_BLOCKS, 512 threads (8 waves).
//
// Key change vs previous: the inner loops only ever touch A[:, tyi, :] and
// P[:, tyi, :] for the (at most 2) fixed row-types of the block. Those slices
// (50x64 floats each) are staged into LDS interleaved as float2(A,P), so the
// hot loop is pure LDS: ds_read_b64(ev, uniform) + ds_read_b64(AP) +
// ds_read_b32(ej) + ~10 VALU. No global loads, no 64-bit address arithmetic.
// LDS = 70.2 KB -> 2 blocks/CU (16 waves/CU resident).
//
// LL blocks: batch b, row pair (ih, 255-ih) -> uniform 255 inner iters/block,
// waves split each row's j-loop stride-8.
// Integral blocks: (b,k) per block, waves split the i-loop, invalid events
// predicated out.
// ---------------------------------------------------------------------------
__global__ __launch_bounds__(NTHREADS) void main_kernel(
    const float* __restrict__ times, const int* __restrict__ types,
    const int* __restrict__ Tp,
    const float* __restrict__ emb,  const float* __restrict__ a,
    const float* __restrict__ Amat, const float* __restrict__ Pmat,
    float* __restrict__ ws_ll, float* __restrict__ ws_int)
{
    const int tid = threadIdx.x;
    const int e   = tid & 63;
    const int w   = tid >> 6;
    const int bid = blockIdx.x;
    const bool is_ll = (bid < LL_BLOCKS);
    const int b = is_ll ? (bid / (S / 2)) : ((bid - LL_BLOCKS) / NT);

    __shared__ __align__(16) float  s_emb[NTE];     // 12.8 KB
    __shared__ __align__(16) float2 s_AP[2][NTE];   // 51.2 KB  (A,P) slices
    __shared__ float2 s_ev[S];                      // 2 KB (t, ty*E as bits)
    __shared__ float  s_part[2][NW][E];             // 4 KB
    __shared__ float  s_row[2];

    // row types for the slices (uniform scalar loads)
    int ty0, ty1;
    if (is_ll) {
        const int ih = bid % (S / 2);
        ty0 = types[b * S + ih];
        ty1 = types[b * S + (S - 1 - ih)];
    } else {
        ty0 = (bid - LL_BLOCKS) % NT;   // k
        ty1 = ty0;
    }

    // stage emb with float4 (800 vec4 loads across 512 threads)
    {
        const float4* __restrict__ emb4 = (const float4*)emb;
        float4* s4 = (float4*)s_emb;
        for (int idx = tid; idx < NTE / 4; idx += NTHREADS)
            s4[idx] = emb4[idx];
    }
    // stage A/P slices: s_AP[r][ty*64+e] = (A[ty][tyi_r][e], P[ty][tyi_r][e])
    for (int idx = tid; idx < NTE; idx += NTHREADS) {
        const int row = idx >> 6, col = idx & 63;
        const int g0 = row * NTE + ty0 * E + col;
        s_AP[0][idx] = make_float2(Amat[g0], Pmat[g0]);
        if (is_ll) {
            const int g1 = row * NTE + ty1 * E + col;
            s_AP[1][idx] = make_float2(Amat[g1], Pmat[g1]);
        }
    }
    for (int j = tid; j < S; j += NTHREADS)
        s_ev[j] = make_float2(times[b * S + j],
                              __int_as_float(types[b * S + j] * E));
    __syncthreads();

    if (is_ll) {
        const int ih = bid % (S / 2);
        const int rows[2] = { ih, S - 1 - ih };
        #pragma unroll
        for (int r = 0; r < 2; ++r) {
            const int   i      = rows[r];
            const float t_i    = s_ev[i].x;
            const int   col    = __float_as_int(s_ev[i].y) + e;  // tyi*E + e
            const float negEi2 = -s_emb[col] * LOG2E;            // fold log2e

            float macc = 0.0f;
            #pragma unroll 8
            for (int j = w; j < i; j += NW) {
                const float2 ev   = s_ev[j];                     // uniform b64
                const float  dtj  = t_i - ev.x;
                const int    sidx = __float_as_int(ev.y) + e;    // tyj*E + e
                const float  ej   = s_emb[sidx];                 // b32
                const float2 ap   = s_AP[r][sidx];               // b64 (A,P)
                macc = fmaf(ap.x * ej, exp2f(negEi2 * ap.y * ej * dtj), macc);
            }
            s_part[r][w][e] = macc;
        }
        __syncthreads();
        if (w < 2) {
            const int   i     = rows[w];
            const float t_i   = s_ev[i].x;
            const int   col   = __float_as_int(s_ev[i].y) + e;
            const float emb_i = s_emb[col];
            float mt = 0.0f;
            #pragma unroll
            for (int q = 0; q < NW; ++q) mt += s_part[w][q][e];
            const float sp    = softplus(fmaf(emb_i, mt, emb_i * a[col]));
            const float inten = wave_reduce_sum(sp);
            if (e == 0)
                s_row[w] = (t_i >= 0.0f) ? logf(inten + EPSF) : 0.0f;
        }
        __syncthreads();
        if (tid == 0) ws_ll[bid] = s_row[0] + s_row[1];
    } else {
        const float Tf     = (float)(*Tp);
        const int   colk   = ty0 * E + e;
        const float embk   = s_emb[colk];
        const float negEk2 = -embk * LOG2E;

        float acc = 0.0f;
        #pragma unroll 8
        for (int i = w; i < S; i += NW) {
            const float2 ev   = s_ev[i];
            const float  dT   = Tf - ev.x;
            const int    sidx = __float_as_int(ev.y) + e;
            const float  et   = s_emb[sidx];
            const float2 ap   = s_AP[0][sidx];
            const float  c    = ap.x * et * exp2f(negEk2 * ap.y * et * dT);
            acc += (ev.x >= 0.0f) ? c : 0.0f;   // predicated, no branch
        }
        s_part[0][w][e] = acc;
        __syncthreads();
        if (w == 0) {
            float mt = 0.0f;
            #pragma unroll
            for (int q = 0; q < NW; ++q) mt += s_part[0][q][e];
            const float sp = softplus(fmaf(embk, mt, embk * a[colk]));
            const float s  = wave_reduce_sum(sp);
            if (e == 0) ws_int[bid - LL_BLOCKS] = s;
        }
    }
}

// ---------------------------------------------------------------------------
// Finalize: one block, 4 waves. Tree-reduce ll partials + base_sum via LDS;
// per-batch min/max/intenT via one wave each (shuffle reductions).
// out = integral - ll
// ---------------------------------------------------------------------------
__global__ __launch_bounds__(256) void finalize_kernel(
    const float* __restrict__ times,
    const int* __restrict__ Tp,
    const float* __restrict__ emb, const float* __restrict__ a,
    const float* __restrict__ ws_ll, const float* __restrict__ ws_int,
    float* __restrict__ out)
{
    const int t    = threadIdx.x;
    const int lane = t & 63;
    const int w    = t >> 6;
    const float Tf = (float)(*Tp);

    float llp = 0.0f;
    for (int idx = t; idx < LL_BLOCKS; idx += 256) llp += ws_ll[idx];
    float bs = 0.0f;
    for (int idx = t; idx < NTE; idx += 256) bs += softplus(emb[idx] * a[idx]);

    __shared__ float red[256], red2[256];
    red[t] = llp; red2[t] = bs;

    __shared__ float s_first[B], s_last[B], s_iT[B], s_any[B];
    for (int b = w; b < B; b += 4) {
        float mn = 1e30f, mx = -1e30f;
        #pragma unroll
        for (int q = 0; q < S / 64; ++q) {
            const float tv = times[b * S + q * 64 + lane];
            const bool valid = (tv >= 0.0f);
            mn = fminf(mn, valid ? tv : 1e30f);
            mx = fmaxf(mx, valid ? tv : -1e30f);
        }
        float iv = (lane < NT) ? ws_int[b * NT + lane] : 0.0f;
        #pragma unroll
        for (int off = 32; off > 0; off >>= 1) {
            mn = fminf(mn, __shfl_down(mn, off, 64));
            mx = fmaxf(mx, __shfl_down(mx, off, 64));
            iv += __shfl_down(iv, off, 64);
        }
        if (lane == 0) {
            const bool any_valid = (mn < 1e29f);
            s_any[b]   = any_valid ? 1.0f : 0.0f;
            s_first[b] = any_valid ? mn : 0.0f;
            s_last[b]  = any_valid ? mx : 0.0f;
            s_iT[b]    = iv;
        }
    }
    __syncthreads();

    for (int off = 128; off > 0; off >>= 1) {
        if (t < off) { red[t] += red[t + off]; red2[t] += red2[t + off]; }
        __syncthreads();
    }

    if (t == 0) {
        const float base_sum = red2[0];
        float integral = 0.0f;
        #pragma unroll
        for (int b = 0; b < B; ++b) {
            integral += (s_any[b] > 0.5f)
                ? s_iT[b] * (Tf - s_last[b]) + base_sum * s_first[b]
                : base_sum * Tf;
        }
        out[0] = integral - red[0];
    }
}

extern "C" void kernel_launch(void* const* d_in, const int* in_sizes, int n_in,
                              void* d_out, int out_size, void* d_ws, size_t ws_size,
                              hipStream_t stream) {
    const float* times = (const float*)d_in[0];
    const int*   types = (const int*)d_in[1];
    const int*   Tp    = (const int*)d_in[2];
    const float* emb   = (const float*)d_in[3];
    const float* a     = (const float*)d_in[4];
    const float* Amat  = (const float*)d_in[5];
    const float* Pmat  = (const float*)d_in[6];

    float* ws     = (float*)d_ws;
    float* ws_ll  = ws;                  // [0, 1024)
    float* ws_int = ws + LL_BLOCKS;      // [1024, 1424)
    float* out    = (float*)d_out;

    main_kernel<<<LL_BLOCKS + IN_BLOCKS, NTHREADS, 0, stream>>>(
        times, types, Tp, emb, a, Amat, Pmat, ws_ll, ws_int);
    finalize_kernel<<<1, 256, 0, stream>>>(times, Tp, emb, a, ws_ll, ws_int, out);
}

// Round 3
// 91.903 us; speedup vs baseline: 1.2048x; 1.0664x over previous
//
#include <hip/hip_runtime.h>
#include <math.h>

#define B   8
#define S   256
#define NT  50
#define E   64
#define NTE (NT * E)
#define EPSF 1e-16f
#define LOG2E 1.4426950408889634f

#define NW        4                 // waves per block
#define NTHREADS  (64 * NW)
#define LL_BLOCKS (B * S / 2)       // 1024 blocks; each handles rows (ih, S-1-ih)
#define IN_BLOCKS (B * NT)          // 400 blocks
#define TAB_ELEMS (NT * NTE)        // 160000 float2 = 1.25 MB

__device__ __forceinline__ float softplus(float x) {
    if (x > 20.0f) return x;
    return log1pf(__expf(x));
}

__device__ __forceinline__ float wave_reduce_sum(float v) {
    #pragma unroll
    for (int off = 32; off > 0; off >>= 1)
        v += __shfl_down(v, off, 64);
    return v;  // lane 0 holds the sum
}

// ---------------------------------------------------------------------------
// Prekernel: fused table AEPE[tyj*NTE + tyi*E + e] = (A*ej, P*ej) where
// ej = emb[tyj*E + e]. 1.25 MB, L2-resident, amortized across all main blocks.
// Removes one load stream + one LDS read + 2 muls from every hot iteration.
// ---------------------------------------------------------------------------
__global__ __launch_bounds__(256) void pre_kernel(
    const float* __restrict__ emb,
    const float* __restrict__ Amat, const float* __restrict__ Pmat,
    float2* __restrict__ tab)
{
    const int i   = blockIdx.x * 256 + threadIdx.x;   // < TAB_ELEMS
    const int tyj = i / NTE;
    const float ej = emb[tyj * E + (i & 63)];
    tab[i] = make_float2(Amat[i] * ej, Pmat[i] * ej);
}

// ---------------------------------------------------------------------------
// Main kernel. Grid = LL_BLOCKS + IN_BLOCKS, 256 threads (4 waves).
// Inner loop per (i,j,e): 1 uniform LDS read (event rec) + 1 coalesced
// global_load_dwordx2 from the fused table + sub/mul/mul/exp2/fma.
// No s_emb staging (table folds ej); LDS ~5 KB -> 8 blocks/CU, whole grid
// resident. LL blocks: row pair (ih, 255-ih) = uniform 255 iters/block.
// ---------------------------------------------------------------------------
__global__ __launch_bounds__(NTHREADS) void main_kernel(
    const float* __restrict__ times, const int* __restrict__ types,
    const int* __restrict__ Tp,
    const float* __restrict__ emb,  const float* __restrict__ a,
    const float2* __restrict__ tab,
    float* __restrict__ ws_ll, float* __restrict__ ws_int)
{
    const int tid = threadIdx.x;
    const int e   = tid & 63;
    const int w   = tid >> 6;
    const int bid = blockIdx.x;
    const bool is_ll = (bid < LL_BLOCKS);
    const int b = is_ll ? (bid / (S / 2)) : ((bid - LL_BLOCKS) / NT);

    __shared__ __align__(16) float4 s_ev[S];   // (t, ty*E, ty*NTE, 0) as bits
    __shared__ float s_part[2][NW][E];
    __shared__ float s_row[2];

    for (int j = tid; j < S; j += NTHREADS) {
        const int ty = types[b * S + j];
        s_ev[j] = make_float4(times[b * S + j],
                              __int_as_float(ty * E),
                              __int_as_float(ty * NTE), 0.0f);
    }
    __syncthreads();

    if (is_ll) {
        const int ih = bid % (S / 2);
        const int rows[2] = { ih, S - 1 - ih };
        #pragma unroll
        for (int r = 0; r < 2; ++r) {
            const int   i      = rows[r];
            const float t_i    = s_ev[i].x;
            const int   col    = __float_as_int(s_ev[i].y) + e;  // tyi*E + e
            const float negEi2 = -emb[col] * LOG2E;              // L2-hot, once

            float macc = 0.0f;
            #pragma unroll 8
            for (int j = w; j < i; j += NW) {
                const float4 ev  = s_ev[j];                      // uniform b128
                const float  dtj = t_i - ev.x;
                const int    idx = __float_as_int(ev.z) + col;   // tyj*NTE+col
                const float2 ap  = tab[idx];                     // dwordx2
                macc = fmaf(ap.x, exp2f(negEi2 * ap.y * dtj), macc);
            }
            s_part[r][w][e] = macc;
        }
        __syncthreads();
        if (w < 2) {
            const int   i     = rows[w];
            const float t_i   = s_ev[i].x;
            const int   col   = __float_as_int(s_ev[i].y) + e;
            const float emb_i = emb[col];
            float mt = 0.0f;
            #pragma unroll
            for (int q = 0; q < NW; ++q) mt += s_part[w][q][e];
            const float sp    = softplus(fmaf(emb_i, mt, emb_i * a[col]));
            const float inten = wave_reduce_sum(sp);
            if (e == 0)
                s_row[w] = (t_i >= 0.0f) ? logf(inten + EPSF) : 0.0f;
        }
        __syncthreads();
        if (tid == 0) ws_ll[bid] = s_row[0] + s_row[1];
    } else {
        const int   k      = (bid - LL_BLOCKS) % NT;
        const float Tf     = (float)(*Tp);
        const int   colk   = k * E + e;
        const float embk   = emb[colk];
        const float negEk2 = -embk * LOG2E;

        float acc = 0.0f;
        #pragma unroll 8
        for (int i = w; i < S; i += NW) {
            const float4 ev  = s_ev[i];
            const float  dT  = Tf - ev.x;
            const int    idx = __float_as_int(ev.z) + colk;  // ty_i*NTE + k*E+e
            const float2 ap  = tab[idx];
            const float  c   = ap.x * exp2f(negEk2 * ap.y * dT);
            acc += (ev.x >= 0.0f) ? c : 0.0f;   // predicated, no branch
        }
        s_part[0][w][e] = acc;
        __syncthreads();
        if (w == 0) {
            float mt = 0.0f;
            #pragma unroll
            for (int q = 0; q < NW; ++q) mt += s_part[0][q][e];
            const float sp = softplus(fmaf(embk, mt, embk * a[colk]));
            const float s  = wave_reduce_sum(sp);
            if (e == 0) ws_int[bid - LL_BLOCKS] = s;
        }
    }
}

// ---------------------------------------------------------------------------
// Finalize: one block, 4 waves. Tree-reduce ll partials + base_sum via LDS;
// per-batch min/max/intenT via one wave each (shuffle reductions).
// out = integral - ll
// ---------------------------------------------------------------------------
__global__ __launch_bounds__(256) void finalize_kernel(
    const float* __restrict__ times,
    const int* __restrict__ Tp,
    const float* __restrict__ emb, const float* __restrict__ a,
    const float* __restrict__ ws_ll, const float* __restrict__ ws_int,
    float* __restrict__ out)
{
    const int t    = threadIdx.x;
    const int lane = t & 63;
    const int w    = t >> 6;
    const float Tf = (float)(*Tp);

    float llp = 0.0f;
    for (int idx = t; idx < LL_BLOCKS; idx += 256) llp += ws_ll[idx];
    float bs = 0.0f;
    for (int idx = t; idx < NTE; idx += 256) bs += softplus(emb[idx] * a[idx]);

    __shared__ float red[256], red2[256];
    red[t] = llp; red2[t] = bs;

    __shared__ float s_first[B], s_last[B], s_iT[B], s_any[B];
    for (int b = w; b < B; b += 4) {
        float mn = 1e30f, mx = -1e30f;
        #pragma unroll
        for (int q = 0; q < S / 64; ++q) {
            const float tv = times[b * S + q * 64 + lane];
            const bool valid = (tv >= 0.0f);
            mn = fminf(mn, valid ? tv : 1e30f);
            mx = fmaxf(mx, valid ? tv : -1e30f);
        }
        float iv = (lane < NT) ? ws_int[b * NT + lane] : 0.0f;
        #pragma unroll
        for (int off = 32; off > 0; off >>= 1) {
            mn = fminf(mn, __shfl_down(mn, off, 64));
            mx = fmaxf(mx, __shfl_down(mx, off, 64));
            iv += __shfl_down(iv, off, 64);
        }
        if (lane == 0) {
            const bool any_valid = (mn < 1e29f);
            s_any[b]   = any_valid ? 1.0f : 0.0f;
            s_first[b] = any_valid ? mn : 0.0f;
            s_last[b]  = any_valid ? mx : 0.0f;
            s_iT[b]    = iv;
        }
    }
    __syncthreads();

    for (int off = 128; off > 0; off >>= 1) {
        if (t < off) { red[t] += red[t + off]; red2[t] += red2[t + off]; }
        __syncthreads();
    }

    if (t == 0) {
        const float base_sum = red2[0];
        float integral = 0.0f;
        #pragma unroll
        for (int b = 0; b < B; ++b) {
            integral += (s_any[b] > 0.5f)
                ? s_iT[b] * (Tf - s_last[b]) + base_sum * s_first[b]
                : base_sum * Tf;
        }
        out[0] = integral - red[0];
    }
}

extern "C" void kernel_launch(void* const* d_in, const int* in_sizes, int n_in,
                              void* d_out, int out_size, void* d_ws, size_t ws_size,
                              hipStream_t stream) {
    const float* times = (const float*)d_in[0];
    const int*   types = (const int*)d_in[1];
    const int*   Tp    = (const int*)d_in[2];
    const float* emb   = (const float*)d_in[3];
    const float* a     = (const float*)d_in[4];
    const float* Amat  = (const float*)d_in[5];
    const float* Pmat  = (const float*)d_in[6];

    float*  ws     = (float*)d_ws;
    float*  ws_ll  = ws;                    // [0, 1024)
    float*  ws_int = ws + LL_BLOCKS;        // [1024, 1424)
    float2* tab    = (float2*)(ws + 2048);  // 8 KB offset, 1.25 MB table
    float*  out    = (float*)d_out;

    pre_kernel<<<TAB_ELEMS / 256, 256, 0, stream>>>(emb, Amat, Pmat, tab);
    main_kernel<<<LL_BLOCKS + IN_BLOCKS, NTHREADS, 0, stream>>>(
        times, types, Tp, emb, a, tab, ws_ll, ws_int);
    finalize_kernel<<<1, 256, 0, stream>>>(times, Tp, emb, a, ws_ll, ws_int, out);
}